// Round 1
// baseline (187.256 us; speedup 1.0000x reference)
//
#include <hip/hip_runtime.h>
#include <hip/hip_bf16.h>

#define B_ 4
#define S_ 4096
#define DIN 512
#define DOUT 64
#define QB 64
#define KVB 64

typedef __attribute__((ext_vector_type(8))) short short8;
typedef __attribute__((ext_vector_type(4))) float f32x4;

static __device__ __forceinline__ unsigned short f2bf(float x) {
    union { float f; unsigned u; } v; v.f = x;
    unsigned r = v.u + 0x7FFF + ((v.u >> 16) & 1);  // round-to-nearest-even
    return (unsigned short)(r >> 16);
}

// ---------------------------------------------------------------------------
// Kernel 0: W [512][64] fp32  ->  Wt [64][512] bf16 (x3 weights)
// ---------------------------------------------------------------------------
__global__ void wt_kernel(const float* __restrict__ Wq, const float* __restrict__ Wk,
                          const float* __restrict__ Wv, unsigned short* __restrict__ wt) {
    int p = blockIdx.x;  // 0:q 1:k 2:v
    const float* w = (p == 0) ? Wq : ((p == 1) ? Wk : Wv);
    unsigned short* o = wt + (size_t)p * DIN * DOUT;
    for (int i = threadIdx.x; i < DIN * DOUT; i += blockDim.x) {
        int k = i >> 6, d = i & 63;
        o[d * DIN + k] = f2bf(w[i]);
    }
}

// ---------------------------------------------------------------------------
// Kernel 1: projections. grid (16384/64, 3), 256 thr (4 waves x 16 rows).
// p=0: Q = query@Wq -> qb[s][64] ; p=1: K = key@Wk -> kb[s][64]
// p=2: V = value@Wv -> vtb[b][d][s]  (transposed for PV B-operand reads)
// ---------------------------------------------------------------------------
__global__ __launch_bounds__(256) void proj_kernel(
    const float* __restrict__ q_in, const float* __restrict__ k_in,
    const float* __restrict__ v_in, const unsigned short* __restrict__ wt,
    unsigned short* __restrict__ qb, unsigned short* __restrict__ kb,
    unsigned short* __restrict__ vtb)
{
    int p = blockIdx.y;
    const float* in = (p == 0) ? q_in : ((p == 1) ? k_in : v_in);
    const unsigned short* w = wt + (size_t)p * DIN * DOUT;
    int tid = threadIdx.x, wv = tid >> 6, lane = tid & 63;
    int lrow = lane & 15, lkhi = lane >> 4;
    int m0 = blockIdx.x * 64 + wv * 16;
    const float* arow = in + (size_t)(m0 + lrow) * DIN + lkhi * 8;

    f32x4 acc[4] = {};
    for (int k0 = 0; k0 < DIN; k0 += 32) {
        float4 a0 = *reinterpret_cast<const float4*>(arow + k0);
        float4 a1 = *reinterpret_cast<const float4*>(arow + k0 + 4);
        short8 af;
        af[0] = f2bf(a0.x); af[1] = f2bf(a0.y); af[2] = f2bf(a0.z); af[3] = f2bf(a0.w);
        af[4] = f2bf(a1.x); af[5] = f2bf(a1.y); af[6] = f2bf(a1.z); af[7] = f2bf(a1.w);
        for (int ct = 0; ct < 4; ++ct) {
            short8 bf = *reinterpret_cast<const short8*>(
                w + (size_t)(ct * 16 + lrow) * DIN + k0 + lkhi * 8);
            acc[ct] = __builtin_amdgcn_mfma_f32_16x16x32_bf16(af, bf, acc[ct], 0, 0, 0);
        }
    }
    for (int ct = 0; ct < 4; ++ct) {
        for (int r = 0; r < 4; ++r) {
            int row = m0 + lkhi * 4 + r;       // global flat s index
            int col = ct * 16 + lrow;          // output dim
            unsigned short val = f2bf(acc[ct][r]);
            if (p == 0)       qb[(size_t)row * DOUT + col] = val;
            else if (p == 1)  kb[(size_t)row * DOUT + col] = val;
            else {
                int b = row >> 12, s = row & 4095;
                vtb[((size_t)b * DOUT + col) * S_ + s] = val;
            }
        }
    }
}

// ---------------------------------------------------------------------------
// Kernel 2: causal flash attention. grid (S/64, B), 256 thr (4 waves x 16 q-rows)
// ---------------------------------------------------------------------------
__global__ __launch_bounds__(256) void attn_kernel(
    const unsigned short* __restrict__ qb, const unsigned short* __restrict__ kb,
    const unsigned short* __restrict__ vtb, float* __restrict__ out)
{
    __shared__ unsigned short k_lds[KVB * DOUT];      // swizzled [kv][d]
    __shared__ unsigned short v_lds[DOUT * KVB];      // swizzled [d][kv]
    __shared__ unsigned short p_lds[4][16 * KVB];     // per-wave swizzled [qrow][kv]

    int b = blockIdx.y, qt = blockIdx.x;
    int q0 = qt * QB;
    int tid = threadIdx.x, wv = tid >> 6, lane = tid & 63;
    int lrow = lane & 15, lkhi = lane >> 4;

    const unsigned short* Qbase = qb + ((size_t)b * S_ + q0 + wv * 16 + lrow) * DOUT;
    short8 qf[2];
    qf[0] = *reinterpret_cast<const short8*>(Qbase + lkhi * 8);
    qf[1] = *reinterpret_cast<const short8*>(Qbase + 32 + lkhi * 8);

    f32x4 o[4] = {};
    float m_run[4], l_run[4];
    for (int r = 0; r < 4; ++r) { m_run[r] = -INFINITY; l_run[r] = 0.f; }

    int srow = tid >> 3;           // 0..31 staging row
    int scol = (tid & 7) * 8;      // 0..56 staging col (bf16 elems)
    const unsigned short* Kg = kb + (size_t)b * S_ * DOUT;
    const unsigned short* Vg = vtb + (size_t)b * DOUT * S_;
    char* kl = reinterpret_cast<char*>(k_lds);
    char* vl = reinterpret_cast<char*>(v_lds);
    char* pw = reinterpret_cast<char*>(p_lds[wv]);

    int nkv = qt + 1;
    for (int kvt = 0; kvt < nkv; ++kvt) {
        int kv0 = kvt * KVB;
        for (int half = 0; half < 2; ++half) {
            int r = srow + half * 32;
            int byte = (r * 128 + scol * 2) ^ ((r & 7) << 4);
            short8 kd = *reinterpret_cast<const short8*>(Kg + (size_t)(kv0 + r) * DOUT + scol);
            *reinterpret_cast<short8*>(kl + byte) = kd;
            short8 vd = *reinterpret_cast<const short8*>(Vg + (size_t)r * S_ + kv0 + scol);
            *reinterpret_cast<short8*>(vl + byte) = vd;
        }
        __syncthreads();

        // QK^T: D rows = q-local (lkhi*4+r), cols = kv (ct*16+lrow)
        f32x4 sc[4];
        for (int ct = 0; ct < 4; ++ct) {
            f32x4 a = {};
            for (int ds = 0; ds < 2; ++ds) {
                int r = ct * 16 + lrow;
                int byte = (r * 128 + (ds * 32 + lkhi * 8) * 2) ^ ((r & 7) << 4);
                short8 kf = *reinterpret_cast<const short8*>(kl + byte);
                a = __builtin_amdgcn_mfma_f32_16x16x32_bf16(qf[ds], kf, a, 0, 0, 0);
            }
            sc[ct] = a;
        }

        // online softmax (per reg-row; cols spread across 16 lanes)
        bool diag = (kvt == qt);
        float corr[4];
        for (int r = 0; r < 4; ++r) {
            int q = q0 + wv * 16 + lkhi * 4 + r;
            float mx = -INFINITY;
            for (int ct = 0; ct < 4; ++ct) {
                float v = sc[ct][r] * 0.125f;
                if (diag && (kv0 + ct * 16 + lrow) > q) v = -INFINITY;
                sc[ct][r] = v;
                mx = fmaxf(mx, v);
            }
            mx = fmaxf(mx, __shfl_xor(mx, 1));
            mx = fmaxf(mx, __shfl_xor(mx, 2));
            mx = fmaxf(mx, __shfl_xor(mx, 4));
            mx = fmaxf(mx, __shfl_xor(mx, 8));
            float mnew = fmaxf(m_run[r], mx);
            corr[r] = __expf(m_run[r] - mnew);
            float rs = 0.f;
            for (int ct = 0; ct < 4; ++ct) {
                float pv = __expf(sc[ct][r] - mnew);
                sc[ct][r] = pv;
                rs += pv;
            }
            rs += __shfl_xor(rs, 1);
            rs += __shfl_xor(rs, 2);
            rs += __shfl_xor(rs, 4);
            rs += __shfl_xor(rs, 8);
            l_run[r] = l_run[r] * corr[r] + rs;
            m_run[r] = mnew;
        }
        for (int ct2 = 0; ct2 < 4; ++ct2)
            for (int r = 0; r < 4; ++r)
                o[ct2][r] *= corr[r];

        // P (C-layout) -> per-wave LDS (A-layout source), bf16
        for (int ct = 0; ct < 4; ++ct) {
            for (int r = 0; r < 4; ++r) {
                int qr = lkhi * 4 + r;
                int col = ct * 16 + lrow;
                int byte = (qr * 128 + col * 2) ^ ((qr & 7) << 4);
                *reinterpret_cast<unsigned short*>(pw + byte) = f2bf(sc[ct][r]);
            }
        }

        // PV: A = P (rows=q), B = Vt (cols=d, k=kv contiguous)
        for (int ct2 = 0; ct2 < 4; ++ct2) {
            for (int ks = 0; ks < 2; ++ks) {
                int pbyte = (lrow * 128 + (ks * 32 + lkhi * 8) * 2) ^ ((lrow & 7) << 4);
                short8 pf = *reinterpret_cast<const short8*>(pw + pbyte);
                int vr = ct2 * 16 + lrow;
                int vbyte = (vr * 128 + (ks * 32 + lkhi * 8) * 2) ^ ((vr & 7) << 4);
                short8 vf = *reinterpret_cast<const short8*>(vl + vbyte);
                o[ct2] = __builtin_amdgcn_mfma_f32_16x16x32_bf16(pf, vf, o[ct2], 0, 0, 0);
            }
        }
        __syncthreads();
    }

    // epilogue: Z = O / l, fp32 out
    for (int r = 0; r < 4; ++r) {
        int q = q0 + wv * 16 + lkhi * 4 + r;
        float inv = 1.f / l_run[r];
        for (int ct2 = 0; ct2 < 4; ++ct2)
            out[((size_t)(b * S_ + q)) * DOUT + ct2 * 16 + lrow] = o[ct2][r] * inv;
    }
}

extern "C" void kernel_launch(void* const* d_in, const int* in_sizes, int n_in,
                              void* d_out, int out_size, void* d_ws, size_t ws_size,
                              hipStream_t stream) {
    const float* key_in = (const float*)d_in[0];
    const float* val_in = (const float*)d_in[1];
    const float* qry_in = (const float*)d_in[2];
    const float* Wk = (const float*)d_in[3];
    const float* Wv = (const float*)d_in[4];
    const float* Wq = (const float*)d_in[5];
    float* out = (float*)d_out;

    unsigned short* qb  = (unsigned short*)d_ws;                 // [B*S][64] bf16
    unsigned short* kb  = qb  + (size_t)B_ * S_ * DOUT;          // [B*S][64] bf16
    unsigned short* vtb = kb  + (size_t)B_ * S_ * DOUT;          // [B][64][S] bf16
    unsigned short* wt  = vtb + (size_t)B_ * S_ * DOUT;          // [3][64][512] bf16

    wt_kernel<<<3, 256, 0, stream>>>(Wq, Wk, Wv, wt);
    proj_kernel<<<dim3(256, 3), 256, 0, stream>>>(qry_in, key_in, val_in, wt, qb, kb, vtb);
    attn_kernel<<<dim3(S_ / QB, B_), 256, 0, stream>>>(qb, kb, vtb, out);
}

// Round 2
// 131.999 us; speedup vs baseline: 1.4186x; 1.4186x over previous
//
#include <hip/hip_runtime.h>
#include <hip/hip_bf16.h>

#define B_ 4
#define S_ 4096
#define DIN 512
#define DOUT 64
#define QB 64
#define KVB 64
#define NCHUNK_TOT 288   // sum over qt of ceil((qt+1)/8)

typedef __attribute__((ext_vector_type(8))) short short8;
typedef __attribute__((ext_vector_type(4))) float f32x4;

static __device__ __forceinline__ unsigned short f2bf(float x) {
    union { float f; unsigned u; } v; v.f = x;
    unsigned r = v.u + 0x7FFF + ((v.u >> 16) & 1);  // round-to-nearest-even
    return (unsigned short)(r >> 16);
}

// ---------------------------------------------------------------------------
// Kernel 0: W [512][64] fp32  ->  Wt [64][512] bf16 (x3 weights)
// ---------------------------------------------------------------------------
__global__ void wt_kernel(const float* __restrict__ Wq, const float* __restrict__ Wk,
                          const float* __restrict__ Wv, unsigned short* __restrict__ wt) {
    int p = blockIdx.x;  // 0:q 1:k 2:v
    const float* w = (p == 0) ? Wq : ((p == 1) ? Wk : Wv);
    unsigned short* o = wt + (size_t)p * DIN * DOUT;
    for (int i = threadIdx.x; i < DIN * DOUT; i += blockDim.x) {
        int k = i >> 6, d = i & 63;
        o[d * DIN + k] = f2bf(w[i]);
    }
}

// ---------------------------------------------------------------------------
// Kernel 1: projections. grid (16384/64, 3), 256 thr (4 waves x 16 rows).
// p=0: Q = (query@Wq)*0.125 -> qb   (1/sqrt(64) folded in; exact in bf16)
// p=1: K = key@Wk -> kb ; p=2: V = value@Wv -> vtb[b][d][s] (transposed)
// ---------------------------------------------------------------------------
__global__ __launch_bounds__(256) void proj_kernel(
    const float* __restrict__ q_in, const float* __restrict__ k_in,
    const float* __restrict__ v_in, const unsigned short* __restrict__ wt,
    unsigned short* __restrict__ qb, unsigned short* __restrict__ kb,
    unsigned short* __restrict__ vtb)
{
    int p = blockIdx.y;
    const float* in = (p == 0) ? q_in : ((p == 1) ? k_in : v_in);
    const unsigned short* w = wt + (size_t)p * DIN * DOUT;
    int tid = threadIdx.x, wv = tid >> 6, lane = tid & 63;
    int lrow = lane & 15, lkhi = lane >> 4;
    int m0 = blockIdx.x * 64 + wv * 16;
    const float* arow = in + (size_t)(m0 + lrow) * DIN + lkhi * 8;

    f32x4 acc[4] = {};
    for (int k0 = 0; k0 < DIN; k0 += 32) {
        float4 a0 = *reinterpret_cast<const float4*>(arow + k0);
        float4 a1 = *reinterpret_cast<const float4*>(arow + k0 + 4);
        short8 af;
        af[0] = f2bf(a0.x); af[1] = f2bf(a0.y); af[2] = f2bf(a0.z); af[3] = f2bf(a0.w);
        af[4] = f2bf(a1.x); af[5] = f2bf(a1.y); af[6] = f2bf(a1.z); af[7] = f2bf(a1.w);
        for (int ct = 0; ct < 4; ++ct) {
            short8 bf = *reinterpret_cast<const short8*>(
                w + (size_t)(ct * 16 + lrow) * DIN + k0 + lkhi * 8);
            acc[ct] = __builtin_amdgcn_mfma_f32_16x16x32_bf16(af, bf, acc[ct], 0, 0, 0);
        }
    }
    float scale = (p == 0) ? 0.125f : 1.0f;
    for (int ct = 0; ct < 4; ++ct) {
        for (int r = 0; r < 4; ++r) {
            int row = m0 + lkhi * 4 + r;       // global flat s index
            int col = ct * 16 + lrow;          // output dim
            unsigned short val = f2bf(acc[ct][r] * scale);
            if (p == 0)       qb[(size_t)row * DOUT + col] = val;
            else if (p == 1)  kb[(size_t)row * DOUT + col] = val;
            else {
                int b = row >> 12, s = row & 4095;
                vtb[((size_t)b * DOUT + col) * S_ + s] = val;
            }
        }
    }
}

// ---------------------------------------------------------------------------
// Kernel 2a: split-KV causal flash attention, phase 1 (partials).
// grid (288, B): blockIdx.x = packed (qt, chunk) id; chunk = 8 kv-tiles.
// Writes unnormalized O plus per-row (m, l).
// ---------------------------------------------------------------------------
__global__ __launch_bounds__(256) void attn_part(
    const unsigned short* __restrict__ qb, const unsigned short* __restrict__ kb,
    const unsigned short* __restrict__ vtb, float* __restrict__ Opart,
    float* __restrict__ ml)
{
    __shared__ unsigned short k_lds[KVB * DOUT];      // swizzled [kv][d]
    __shared__ unsigned short v_lds[DOUT * KVB];      // swizzled [d][kv]
    __shared__ unsigned short p_lds[4][16 * KVB];     // per-wave swizzled [qrow][kv]

    int b = blockIdx.y;
    int x = blockIdx.x;                    // packed chunk id in [0, 288)
    int m = 0;
    while (4 * (m + 1) * (m + 2) <= x) ++m;
    int rem = x - 4 * m * (m + 1);
    int j = rem / (m + 1), c = rem % (m + 1);
    int qt = 8 * m + j;

    int q0 = qt * QB;
    int tid = threadIdx.x, wv = tid >> 6, lane = tid & 63;
    int lrow = lane & 15, lkhi = lane >> 4;

    const unsigned short* Qbase = qb + ((size_t)b * S_ + q0 + wv * 16 + lrow) * DOUT;
    short8 qf[2];
    qf[0] = *reinterpret_cast<const short8*>(Qbase + lkhi * 8);
    qf[1] = *reinterpret_cast<const short8*>(Qbase + 32 + lkhi * 8);

    f32x4 o[4] = {};
    float m_run[4], l_run[4];
    for (int r = 0; r < 4; ++r) { m_run[r] = -INFINITY; l_run[r] = 0.f; }

    int srow = tid >> 3;           // 0..31 staging row
    int scol = (tid & 7) * 8;      // 0..56 staging col (bf16 elems)
    const unsigned short* Kg = kb + (size_t)b * S_ * DOUT;
    const unsigned short* Vg = vtb + (size_t)b * DOUT * S_;
    char* kl = reinterpret_cast<char*>(k_lds);
    char* vl = reinterpret_cast<char*>(v_lds);
    char* pw = reinterpret_cast<char*>(p_lds[wv]);

    int kv_beg = c * 8;
    int kv_end = min(kv_beg + 8, qt + 1);
    for (int kvt = kv_beg; kvt < kv_end; ++kvt) {
        int kv0 = kvt * KVB;
        for (int half = 0; half < 2; ++half) {
            int r = srow + half * 32;
            int byte = (r * 128 + scol * 2) ^ ((r & 7) << 4);
            short8 kd = *reinterpret_cast<const short8*>(Kg + (size_t)(kv0 + r) * DOUT + scol);
            *reinterpret_cast<short8*>(kl + byte) = kd;
            short8 vd = *reinterpret_cast<const short8*>(Vg + (size_t)r * S_ + kv0 + scol);
            *reinterpret_cast<short8*>(vl + byte) = vd;
        }
        __syncthreads();

        // QK^T: D rows = q-local (lkhi*4+r), cols = kv (ct*16+lrow)
        f32x4 sc[4];
        for (int ct = 0; ct < 4; ++ct) {
            f32x4 a = {};
            for (int ds = 0; ds < 2; ++ds) {
                int r = ct * 16 + lrow;
                int byte = (r * 128 + (ds * 32 + lkhi * 8) * 2) ^ ((r & 7) << 4);
                short8 kf = *reinterpret_cast<const short8*>(kl + byte);
                a = __builtin_amdgcn_mfma_f32_16x16x32_bf16(qf[ds], kf, a, 0, 0, 0);
            }
            sc[ct] = a;
        }

        // online softmax (1/sqrt(d) pre-folded into Q)
        bool diag = (kvt == qt);
        float corr[4];
        for (int r = 0; r < 4; ++r) {
            int q = q0 + wv * 16 + lkhi * 4 + r;
            float mx = -INFINITY;
            for (int ct = 0; ct < 4; ++ct) {
                float v = sc[ct][r];
                if (diag && (kv0 + ct * 16 + lrow) > q) v = -INFINITY;
                sc[ct][r] = v;
                mx = fmaxf(mx, v);
            }
            mx = fmaxf(mx, __shfl_xor(mx, 1));
            mx = fmaxf(mx, __shfl_xor(mx, 2));
            mx = fmaxf(mx, __shfl_xor(mx, 4));
            mx = fmaxf(mx, __shfl_xor(mx, 8));
            float mnew = fmaxf(m_run[r], mx);
            corr[r] = __expf(m_run[r] - mnew);
            float rs = 0.f;
            for (int ct = 0; ct < 4; ++ct) {
                float pv = __expf(sc[ct][r] - mnew);
                sc[ct][r] = pv;
                rs += pv;
            }
            rs += __shfl_xor(rs, 1);
            rs += __shfl_xor(rs, 2);
            rs += __shfl_xor(rs, 4);
            rs += __shfl_xor(rs, 8);
            l_run[r] = l_run[r] * corr[r] + rs;
            m_run[r] = mnew;
        }
        for (int ct2 = 0; ct2 < 4; ++ct2)
            for (int r = 0; r < 4; ++r)
                o[ct2][r] *= corr[r];

        // P (C-layout) -> per-wave LDS (A-layout source), bf16
        for (int ct = 0; ct < 4; ++ct) {
            for (int r = 0; r < 4; ++r) {
                int qr = lkhi * 4 + r;
                int col = ct * 16 + lrow;
                int byte = (qr * 128 + col * 2) ^ ((qr & 7) << 4);
                *reinterpret_cast<unsigned short*>(pw + byte) = f2bf(sc[ct][r]);
            }
        }

        // PV: A = P (rows=q), B = Vt (cols=d, k=kv contiguous)
        for (int ct2 = 0; ct2 < 4; ++ct2) {
            for (int ks = 0; ks < 2; ++ks) {
                int pbyte = (lrow * 128 + (ks * 32 + lkhi * 8) * 2) ^ ((lrow & 7) << 4);
                short8 pf = *reinterpret_cast<const short8*>(pw + pbyte);
                int vr = ct2 * 16 + lrow;
                int vbyte = (vr * 128 + (ks * 32 + lkhi * 8) * 2) ^ ((vr & 7) << 4);
                short8 vf = *reinterpret_cast<const short8*>(vl + vbyte);
                o[ct2] = __builtin_amdgcn_mfma_f32_16x16x32_bf16(pf, vf, o[ct2], 0, 0, 0);
            }
        }
        __syncthreads();
    }

    // write partials (unnormalized O + per-row m,l)
    float* Op = Opart + ((size_t)b * NCHUNK_TOT + x) * (64 * 64);
    float* Ml = ml + ((size_t)b * NCHUNK_TOT + x) * (64 * 2);
    for (int r = 0; r < 4; ++r) {
        int qr = wv * 16 + lkhi * 4 + r;
        for (int ct2 = 0; ct2 < 4; ++ct2)
            Op[qr * 64 + ct2 * 16 + lrow] = o[ct2][r];
        if (lrow == 0) {
            Ml[qr * 2 + 0] = m_run[r];
            Ml[qr * 2 + 1] = l_run[r];
        }
    }
}

// ---------------------------------------------------------------------------
// Kernel 2b: combine partials. grid (64 qtiles, B), 256 thr.
// thread -> (row = tid>>2, 16-col group = (tid&3)*16)
// ---------------------------------------------------------------------------
__global__ __launch_bounds__(256) void attn_combine(
    const float* __restrict__ Opart, const float* __restrict__ ml,
    float* __restrict__ out)
{
    int qt = blockIdx.x, b = blockIdx.y;
    int m = qt >> 3;
    int nch = m + 1;
    int cbase = 4 * m * (m + 1) + (qt - 8 * m) * nch;

    int r = threadIdx.x >> 2;
    int cg = (threadIdx.x & 3) * 16;

    float M = -INFINITY;
    for (int c = 0; c < nch; ++c)
        M = fmaxf(M, ml[(((size_t)b * NCHUNK_TOT + cbase + c) * 64 + r) * 2]);

    float L = 0.f;
    f32x4 acc[4] = {};
    for (int c = 0; c < nch; ++c) {
        size_t ci = (size_t)b * NCHUNK_TOT + cbase + c;
        float mc = ml[(ci * 64 + r) * 2 + 0];
        float lc = ml[(ci * 64 + r) * 2 + 1];
        float w = __expf(mc - M);
        L += lc * w;
        const f32x4* Op = reinterpret_cast<const f32x4*>(Opart + ci * (64 * 64) + r * 64 + cg);
        for (int i = 0; i < 4; ++i) {
            f32x4 v = Op[i];
            acc[i] += v * w;
        }
    }
    float inv = 1.f / L;
    f32x4* dst = reinterpret_cast<f32x4*>(out + (((size_t)b * S_) + qt * 64 + r) * DOUT + cg);
    for (int i = 0; i < 4; ++i)
        dst[i] = acc[i] * inv;
}

extern "C" void kernel_launch(void* const* d_in, const int* in_sizes, int n_in,
                              void* d_out, int out_size, void* d_ws, size_t ws_size,
                              hipStream_t stream) {
    const float* key_in = (const float*)d_in[0];
    const float* val_in = (const float*)d_in[1];
    const float* qry_in = (const float*)d_in[2];
    const float* Wk = (const float*)d_in[3];
    const float* Wv = (const float*)d_in[4];
    const float* Wq = (const float*)d_in[5];
    float* out = (float*)d_out;

    char* ws = (char*)d_ws;
    size_t off = 0;
    unsigned short* qb  = (unsigned short*)(ws + off); off += (size_t)B_ * S_ * DOUT * 2;
    unsigned short* kb  = (unsigned short*)(ws + off); off += (size_t)B_ * S_ * DOUT * 2;
    unsigned short* vtb = (unsigned short*)(ws + off); off += (size_t)B_ * S_ * DOUT * 2;
    unsigned short* wt  = (unsigned short*)(ws + off); off += (size_t)3 * DIN * DOUT * 2;
    float* Opart = (float*)(ws + off); off += (size_t)B_ * NCHUNK_TOT * 64 * 64 * 4;
    float* ml    = (float*)(ws + off); off += (size_t)B_ * NCHUNK_TOT * 64 * 2 * 4;

    wt_kernel<<<3, 256, 0, stream>>>(Wq, Wk, Wv, wt);
    proj_kernel<<<dim3(256, 3), 256, 0, stream>>>(qry_in, key_in, val_in, wt, qb, kb, vtb);
    attn_part<<<dim3(NCHUNK_TOT, B_), 256, 0, stream>>>(qb, kb, vtb, Opart, ml);
    attn_combine<<<dim3(S_ / QB, B_), 256, 0, stream>>>(Opart, ml, out);
}

// Round 3
// 94.573 us; speedup vs baseline: 1.9800x; 1.3957x over previous
//
#include <hip/hip_runtime.h>
#include <hip/hip_bf16.h>

#define B_ 4
#define S_ 4096
#define DIN 512
#define DOUT 64
#define QB 64
#define KVB 64
#define NCHUNK_TOT 288   // sum over qt of ceil((qt+1)/8)

typedef __attribute__((ext_vector_type(8))) short short8;
typedef __attribute__((ext_vector_type(4))) float f32x4;

static __device__ __forceinline__ unsigned short f2bf(float x) {
    union { float f; unsigned u; } v; v.f = x;
    unsigned r = v.u + 0x7FFF + ((v.u >> 16) & 1);  // round-to-nearest-even
    return (unsigned short)(r >> 16);
}

static __device__ __forceinline__ void gload_lds16(const void* g, void* l) {
    __builtin_amdgcn_global_load_lds(
        (const __attribute__((address_space(1))) void*)g,
        (__attribute__((address_space(3))) void*)l, 16, 0, 0);
}

// ---------------------------------------------------------------------------
// Kernel 0: W [512][64] fp32 -> Wt [64][512] bf16 (x3). LDS-tiled transpose.
// grid (8, 3) x 256 thr; coalesced loads AND stores.
// ---------------------------------------------------------------------------
__global__ __launch_bounds__(256) void wt_kernel(
    const float* __restrict__ Wq, const float* __restrict__ Wk,
    const float* __restrict__ Wv, unsigned short* __restrict__ wt)
{
    __shared__ float tile[64 * 65];
    int p = blockIdx.y;
    int k0 = blockIdx.x * 64;
    const float* w = (p == 0) ? Wq : ((p == 1) ? Wk : Wv);
    unsigned short* o = wt + (size_t)p * DIN * DOUT;
    int t = threadIdx.x;
    for (int i = 0; i < 16; ++i) {
        int flat = i * 256 + t;
        int ki = flat >> 6, di = flat & 63;
        tile[ki * 65 + di] = w[(size_t)(k0 + ki) * DOUT + di];
    }
    __syncthreads();
    for (int i = 0; i < 16; ++i) {
        int flat = i * 256 + t;
        int d = flat >> 6, k = flat & 63;
        o[(size_t)d * DIN + k0 + k] = f2bf(tile[k * 65 + d]);
    }
}

// ---------------------------------------------------------------------------
// Kernel 1: projections. grid (16384/64, 3), 256 thr (4 waves x 16 rows).
// p=0: Q = (query@Wq)*0.125 -> qb ; p=1: K -> kb ; p=2: V -> vtb[b][d][s]
// ---------------------------------------------------------------------------
__global__ __launch_bounds__(256) void proj_kernel(
    const float* __restrict__ q_in, const float* __restrict__ k_in,
    const float* __restrict__ v_in, const unsigned short* __restrict__ wt,
    unsigned short* __restrict__ qb, unsigned short* __restrict__ kb,
    unsigned short* __restrict__ vtb)
{
    int p = blockIdx.y;
    const float* in = (p == 0) ? q_in : ((p == 1) ? k_in : v_in);
    const unsigned short* w = wt + (size_t)p * DIN * DOUT;
    int tid = threadIdx.x, wv = tid >> 6, lane = tid & 63;
    int lrow = lane & 15, lkhi = lane >> 4;
    int m0 = blockIdx.x * 64 + wv * 16;
    const float* arow = in + (size_t)(m0 + lrow) * DIN + lkhi * 8;

    f32x4 acc[4] = {};
    for (int k0 = 0; k0 < DIN; k0 += 32) {
        float4 a0 = *reinterpret_cast<const float4*>(arow + k0);
        float4 a1 = *reinterpret_cast<const float4*>(arow + k0 + 4);
        short8 af;
        af[0] = f2bf(a0.x); af[1] = f2bf(a0.y); af[2] = f2bf(a0.z); af[3] = f2bf(a0.w);
        af[4] = f2bf(a1.x); af[5] = f2bf(a1.y); af[6] = f2bf(a1.z); af[7] = f2bf(a1.w);
        for (int ct = 0; ct < 4; ++ct) {
            short8 bf = *reinterpret_cast<const short8*>(
                w + (size_t)(ct * 16 + lrow) * DIN + k0 + lkhi * 8);
            acc[ct] = __builtin_amdgcn_mfma_f32_16x16x32_bf16(af, bf, acc[ct], 0, 0, 0);
        }
    }
    float scale = (p == 0) ? 0.125f : 1.0f;
    for (int ct = 0; ct < 4; ++ct) {
        for (int r = 0; r < 4; ++r) {
            int row = m0 + lkhi * 4 + r;       // global flat s index
            int col = ct * 16 + lrow;          // output dim
            unsigned short val = f2bf(acc[ct][r] * scale);
            if (p == 0)       qb[(size_t)row * DOUT + col] = val;
            else if (p == 1)  kb[(size_t)row * DOUT + col] = val;
            else {
                int b = row >> 12, s = row & 4095;
                vtb[((size_t)b * DOUT + col) * S_ + s] = val;
            }
        }
    }
}

// ---------------------------------------------------------------------------
// Kernel 2a: split-KV causal flash attention, phase 1 (partials).
// grid (288, B). Double-buffered K/V via global_load_lds (linear LDS dest,
// inverse-swizzled global source; read side applies the same XOR).
// ---------------------------------------------------------------------------
__global__ __launch_bounds__(256) void attn_part(
    const unsigned short* __restrict__ qb, const unsigned short* __restrict__ kb,
    const unsigned short* __restrict__ vtb, float* __restrict__ Opart,
    float* __restrict__ ml)
{
    __shared__ unsigned short k_lds[2][KVB * DOUT];   // 2 x 8 KB
    __shared__ unsigned short v_lds[2][DOUT * KVB];   // 2 x 8 KB
    __shared__ unsigned short p_lds[4][16 * KVB];     // 8 KB

    int b = blockIdx.y;
    int x = blockIdx.x;                    // packed chunk id in [0, 288)
    int m = 0;
    while (4 * (m + 1) * (m + 2) <= x) ++m;
    int rem = x - 4 * m * (m + 1);
    int j = rem / (m + 1), c = rem % (m + 1);
    int qt = 8 * m + j;

    int q0 = qt * QB;
    int tid = threadIdx.x, wv = tid >> 6, lane = tid & 63;
    int lrow = lane & 15, lkhi = lane >> 4;

    const unsigned short* Qbase = qb + ((size_t)b * S_ + q0 + wv * 16 + lrow) * DOUT;
    short8 qf[2];
    qf[0] = *reinterpret_cast<const short8*>(Qbase + lkhi * 8);
    qf[1] = *reinterpret_cast<const short8*>(Qbase + 32 + lkhi * 8);

    f32x4 o[4] = {};
    float m_run[4], l_run[4];
    for (int r = 0; r < 4; ++r) { m_run[r] = -INFINITY; l_run[r] = 0.f; }

    const unsigned short* Kg = kb + (size_t)b * S_ * DOUT;
    const unsigned short* Vg = vtb + (size_t)b * DOUT * S_;
    char* pw = reinterpret_cast<char*>(p_lds[wv]);

    // staging geometry: wave wv covers rows 16*wv..16*wv+15, 2 calls (h=0,1),
    // lane -> row = 16*wv + 8*h + (lane>>3), 16B chunk = lane&7.
    int srow_lo = (lane >> 3);             // 0..7, == r&7
    int schunk = (lane & 7) * 16;          // within-row byte
    int soff = schunk ^ (srow_lo << 4);    // inverse-swizzled source byte

    int kv_beg = c * 8;
    int kv_end = min(kv_beg + 8, qt + 1);
    int cur = 0;

#define STAGE(buf, kvt_) do {                                                  \
    int kv0_ = (kvt_) * KVB;                                                   \
    for (int h = 0; h < 2; ++h) {                                              \
        int r_ = wv * 16 + h * 8 + srow_lo;                                    \
        const char* gk_ = (const char*)(Kg + (size_t)(kv0_ + r_) * DOUT) + soff; \
        gload_lds16(gk_, (char*)k_lds[buf] + wv * 2048 + h * 1024);            \
        const char* gv_ = (const char*)(Vg + (size_t)r_ * S_ + kv0_) + soff;   \
        gload_lds16(gv_, (char*)v_lds[buf] + wv * 2048 + h * 1024);            \
    }                                                                          \
} while (0)

    STAGE(0, kv_beg);
    asm volatile("s_waitcnt vmcnt(0)" ::: "memory");
    __builtin_amdgcn_s_barrier();
    asm volatile("" ::: "memory");

    for (int kvt = kv_beg; kvt < kv_end; ++kvt) {
        if (kvt + 1 < kv_end) STAGE(cur ^ 1, kvt + 1);  // prefetch flies under compute

        const char* kl = (const char*)k_lds[cur];
        const char* vl = (const char*)v_lds[cur];
        int kv0 = kvt * KVB;

        // QK^T: D rows = q-local (lkhi*4+r), cols = kv (ct*16+lrow)
        f32x4 sc[4];
        for (int ct = 0; ct < 4; ++ct) {
            f32x4 a = {};
            for (int ds = 0; ds < 2; ++ds) {
                int r = ct * 16 + lrow;
                int byte = (r * 128 + (ds * 32 + lkhi * 8) * 2) ^ ((r & 7) << 4);
                short8 kf = *reinterpret_cast<const short8*>(kl + byte);
                a = __builtin_amdgcn_mfma_f32_16x16x32_bf16(qf[ds], kf, a, 0, 0, 0);
            }
            sc[ct] = a;
        }

        // online softmax (1/sqrt(d) pre-folded into Q)
        bool diag = (kvt == qt);
        float corr[4];
        for (int r = 0; r < 4; ++r) {
            int q = q0 + wv * 16 + lkhi * 4 + r;
            float mx = -INFINITY;
            for (int ct = 0; ct < 4; ++ct) {
                float v = sc[ct][r];
                if (diag && (kv0 + ct * 16 + lrow) > q) v = -INFINITY;
                sc[ct][r] = v;
                mx = fmaxf(mx, v);
            }
            mx = fmaxf(mx, __shfl_xor(mx, 1));
            mx = fmaxf(mx, __shfl_xor(mx, 2));
            mx = fmaxf(mx, __shfl_xor(mx, 4));
            mx = fmaxf(mx, __shfl_xor(mx, 8));
            float mnew = fmaxf(m_run[r], mx);
            corr[r] = __expf(m_run[r] - mnew);
            float rs = 0.f;
            for (int ct = 0; ct < 4; ++ct) {
                float pv = __expf(sc[ct][r] - mnew);
                sc[ct][r] = pv;
                rs += pv;
            }
            rs += __shfl_xor(rs, 1);
            rs += __shfl_xor(rs, 2);
            rs += __shfl_xor(rs, 4);
            rs += __shfl_xor(rs, 8);
            l_run[r] = l_run[r] * corr[r] + rs;
            m_run[r] = mnew;
        }
        for (int ct2 = 0; ct2 < 4; ++ct2)
            for (int r = 0; r < 4; ++r)
                o[ct2][r] *= corr[r];

        // P (C-layout) -> per-wave LDS (A-layout source), bf16
        for (int ct = 0; ct < 4; ++ct) {
            for (int r = 0; r < 4; ++r) {
                int qr = lkhi * 4 + r;
                int col = ct * 16 + lrow;
                int byte = (qr * 128 + col * 2) ^ ((qr & 7) << 4);
                *reinterpret_cast<unsigned short*>(pw + byte) = f2bf(sc[ct][r]);
            }
        }

        // PV: A = P (rows=q), B = Vt (cols=d, k=kv contiguous)
        for (int ct2 = 0; ct2 < 4; ++ct2) {
            for (int ks = 0; ks < 2; ++ks) {
                int pbyte = (lrow * 128 + (ks * 32 + lkhi * 8) * 2) ^ ((lrow & 7) << 4);
                short8 pf = *reinterpret_cast<const short8*>(pw + pbyte);
                int vr = ct2 * 16 + lrow;
                int vbyte = (vr * 128 + (ks * 32 + lkhi * 8) * 2) ^ ((vr & 7) << 4);
                short8 vf = *reinterpret_cast<const short8*>(vl + vbyte);
                o[ct2] = __builtin_amdgcn_mfma_f32_16x16x32_bf16(pf, vf, o[ct2], 0, 0, 0);
            }
        }
        __syncthreads();   // loads issued above are long done -> drain is free
        cur ^= 1;
    }
#undef STAGE

    // write partials (unnormalized O + per-row m,l)
    float* Op = Opart + ((size_t)b * NCHUNK_TOT + x) * (64 * 64);
    float* Ml = ml + ((size_t)b * NCHUNK_TOT + x) * (64 * 2);
    for (int r = 0; r < 4; ++r) {
        int qr = wv * 16 + lkhi * 4 + r;
        for (int ct2 = 0; ct2 < 4; ++ct2)
            Op[qr * 64 + ct2 * 16 + lrow] = o[ct2][r];
        if (lrow == 0) {
            Ml[qr * 2 + 0] = m_run[r];
            Ml[qr * 2 + 1] = l_run[r];
        }
    }
}

// ---------------------------------------------------------------------------
// Kernel 2b: combine partials. grid (64 qtiles, B), 256 thr.
// ---------------------------------------------------------------------------
__global__ __launch_bounds__(256) void attn_combine(
    const float* __restrict__ Opart, const float* __restrict__ ml,
    float* __restrict__ out)
{
    int qt = blockIdx.x, b = blockIdx.y;
    int m = qt >> 3;
    int nch = m + 1;
    int cbase = 4 * m * (m + 1) + (qt - 8 * m) * nch;

    int r = threadIdx.x >> 2;
    int cg = (threadIdx.x & 3) * 16;

    float M = -INFINITY;
    for (int c = 0; c < nch; ++c)
        M = fmaxf(M, ml[(((size_t)b * NCHUNK_TOT + cbase + c) * 64 + r) * 2]);

    float L = 0.f;
    f32x4 acc[4] = {};
    for (int c = 0; c < nch; ++c) {
        size_t ci = (size_t)b * NCHUNK_TOT + cbase + c;
        float mc = ml[(ci * 64 + r) * 2 + 0];
        float lc = ml[(ci * 64 + r) * 2 + 1];
        float w = __expf(mc - M);
        L += lc * w;
        const f32x4* Op = reinterpret_cast<const f32x4*>(Opart + ci * (64 * 64) + r * 64 + cg);
        for (int i = 0; i < 4; ++i) {
            f32x4 v = Op[i];
            acc[i] += v * w;
        }
    }
    float inv = 1.f / L;
    f32x4* dst = reinterpret_cast<f32x4*>(out + (((size_t)b * S_) + qt * 64 + r) * DOUT + cg);
    for (int i = 0; i < 4; ++i)
        dst[i] = acc[i] * inv;
}

extern "C" void kernel_launch(void* const* d_in, const int* in_sizes, int n_in,
                              void* d_out, int out_size, void* d_ws, size_t ws_size,
                              hipStream_t stream) {
    const float* key_in = (const float*)d_in[0];
    const float* val_in = (const float*)d_in[1];
    const float* qry_in = (const float*)d_in[2];
    const float* Wk = (const float*)d_in[3];
    const float* Wv = (const float*)d_in[4];
    const float* Wq = (const float*)d_in[5];
    float* out = (float*)d_out;

    char* ws = (char*)d_ws;
    size_t off = 0;
    unsigned short* qb  = (unsigned short*)(ws + off); off += (size_t)B_ * S_ * DOUT * 2;
    unsigned short* kb  = (unsigned short*)(ws + off); off += (size_t)B_ * S_ * DOUT * 2;
    unsigned short* vtb = (unsigned short*)(ws + off); off += (size_t)B_ * S_ * DOUT * 2;
    unsigned short* wt  = (unsigned short*)(ws + off); off += (size_t)3 * DIN * DOUT * 2;
    float* Opart = (float*)(ws + off); off += (size_t)B_ * NCHUNK_TOT * 64 * 64 * 4;
    float* ml    = (float*)(ws + off); off += (size_t)B_ * NCHUNK_TOT * 64 * 2 * 4;

    wt_kernel<<<dim3(8, 3), 256, 0, stream>>>(Wq, Wk, Wv, wt);
    proj_kernel<<<dim3(256, 3), 256, 0, stream>>>(qry_in, key_in, val_in, wt, qb, kb, vtb);
    attn_part<<<dim3(NCHUNK_TOT, B_), 256, 0, stream>>>(qb, kb, vtb, Opart, ml);
    attn_combine<<<dim3(S_ / QB, B_), 256, 0, stream>>>(Opart, ml, out);
}

// Round 6
// 79.988 us; speedup vs baseline: 2.3411x; 1.1823x over previous
//
#include <hip/hip_runtime.h>
#include <hip/hip_bf16.h>

#define B_ 4
#define S_ 4096
#define DIN 512
#define DOUT 64
#define QB 64
#define KVB 64
#define NCHUNK_TOT 288   // sum over qt of ceil((qt+1)/8)

typedef __attribute__((ext_vector_type(8))) short short8;
typedef __attribute__((ext_vector_type(4))) float f32x4;

static __device__ __forceinline__ float fast_exp2(float x) {
    return __builtin_amdgcn_exp2f(x);   // v_exp_f32 (2^x)
}

static __device__ __forceinline__ unsigned short f2bf(float x) {
    union { float f; unsigned u; } v; v.f = x;
    unsigned r = v.u + 0x7FFF + ((v.u >> 16) & 1);  // round-to-nearest-even
    return (unsigned short)(r >> 16);
}

static __device__ __forceinline__ void gload_lds16(const void* g, void* l) {
    __builtin_amdgcn_global_load_lds(
        (const __attribute__((address_space(1))) void*)g,
        (__attribute__((address_space(3))) void*)l, 16, 0, 0);
}

// ---------------------------------------------------------------------------
// Kernel 0: W [512][64] fp32 -> Wt [64][512] bf16 (x3). LDS-tiled transpose.
// ---------------------------------------------------------------------------
__global__ __launch_bounds__(256) void wt_kernel(
    const float* __restrict__ Wq, const float* __restrict__ Wk,
    const float* __restrict__ Wv, unsigned short* __restrict__ wt)
{
    __shared__ float tile[64 * 65];
    int p = blockIdx.y;
    int k0 = blockIdx.x * 64;
    const float* w = (p == 0) ? Wq : ((p == 1) ? Wk : Wv);
    unsigned short* o = wt + (size_t)p * DIN * DOUT;
    int t = threadIdx.x;
    for (int i = 0; i < 16; ++i) {
        int flat = i * 256 + t;
        int ki = flat >> 6, di = flat & 63;
        tile[ki * 65 + di] = w[(size_t)(k0 + ki) * DOUT + di];
    }
    __syncthreads();
    for (int i = 0; i < 16; ++i) {
        int flat = i * 256 + t;
        int d = flat >> 6, k = flat & 63;
        o[(size_t)d * DIN + k0 + k] = f2bf(tile[k * 65 + d]);
    }
}

// ---------------------------------------------------------------------------
// Kernel 1: projections. p=0: Q = (query@Wq)*0.125*log2(e) -> qb  (scores in
// log2 domain so softmax uses raw v_exp_f32); p=1: K -> kb ; p=2: V -> vtb.
// ---------------------------------------------------------------------------
__global__ __launch_bounds__(256) void proj_kernel(
    const float* __restrict__ q_in, const float* __restrict__ k_in,
    const float* __restrict__ v_in, const unsigned short* __restrict__ wt,
    unsigned short* __restrict__ qb, unsigned short* __restrict__ kb,
    unsigned short* __restrict__ vtb)
{
    int p = blockIdx.y;
    const float* in = (p == 0) ? q_in : ((p == 1) ? k_in : v_in);
    const unsigned short* w = wt + (size_t)p * DIN * DOUT;
    int tid = threadIdx.x, wv = tid >> 6, lane = tid & 63;
    int lrow = lane & 15, lkhi = lane >> 4;
    int m0 = blockIdx.x * 64 + wv * 16;
    const float* arow = in + (size_t)(m0 + lrow) * DIN + lkhi * 8;

    f32x4 acc[4] = {};
    for (int k0 = 0; k0 < DIN; k0 += 32) {
        float4 a0 = *reinterpret_cast<const float4*>(arow + k0);
        float4 a1 = *reinterpret_cast<const float4*>(arow + k0 + 4);
        short8 af;
        af[0] = f2bf(a0.x); af[1] = f2bf(a0.y); af[2] = f2bf(a0.z); af[3] = f2bf(a0.w);
        af[4] = f2bf(a1.x); af[5] = f2bf(a1.y); af[6] = f2bf(a1.z); af[7] = f2bf(a1.w);
        for (int ct = 0; ct < 4; ++ct) {
            short8 bf = *reinterpret_cast<const short8*>(
                w + (size_t)(ct * 16 + lrow) * DIN + k0 + lkhi * 8);
            acc[ct] = __builtin_amdgcn_mfma_f32_16x16x32_bf16(af, bf, acc[ct], 0, 0, 0);
        }
    }
    float scale = (p == 0) ? 0.18033688011112042f : 1.0f;  // 0.125 * log2(e)
    for (int ct = 0; ct < 4; ++ct) {
        for (int r = 0; r < 4; ++r) {
            int row = m0 + lkhi * 4 + r;       // global flat s index
            int col = ct * 16 + lrow;          // output dim
            unsigned short val = f2bf(acc[ct][r] * scale);
            if (p == 0)       qb[(size_t)row * DOUT + col] = val;
            else if (p == 1)  kb[(size_t)row * DOUT + col] = val;
            else {
                int b = row >> 12, s = row & 4095;
                vtb[((size_t)b * DOUT + col) * S_ + s] = val;
            }
        }
    }
}

// ---------------------------------------------------------------------------
// Kernel 2a: split-KV causal flash attention, phase 1 (partials).
// Swapped QK^T: sc = mfma(K, Q) -> lane(lrow,lkhi) holds S[q=lrow][kv=ct*16+
// lkhi*4+r]. Row-softmax = in-lane trees + 2 shuffles. Log2 domain.
// ---------------------------------------------------------------------------
__global__ __launch_bounds__(256) void attn_part(
    const unsigned short* __restrict__ qb, const unsigned short* __restrict__ kb,
    const unsigned short* __restrict__ vtb, float* __restrict__ Opart,
    float* __restrict__ ml)
{
    __shared__ unsigned short k_lds[2][KVB * DOUT];   // 2 x 8 KB
    __shared__ unsigned short v_lds[2][DOUT * KVB];   // 2 x 8 KB
    __shared__ unsigned short p_lds[4][16 * KVB];     // 8 KB

    int b = blockIdx.y;
    int x = NCHUNK_TOT - 1 - blockIdx.x;   // longest-first dispatch order
    int m = 0;
    while (4 * (m + 1) * (m + 2) <= x) ++m;
    int rem = x - 4 * m * (m + 1);
    int j = rem / (m + 1), c = rem % (m + 1);
    int qt = 8 * m + j;

    int q0 = qt * QB;
    int tid = threadIdx.x, wv = tid >> 6, lane = tid & 63;
    int lrow = lane & 15, lkhi = lane >> 4;
    int lkhi4 = lkhi * 4;
    int qloc = wv * 16 + lrow;             // q-row (block-local) this lane reduces

    const unsigned short* Qbase = qb + ((size_t)b * S_ + q0 + wv * 16 + lrow) * DOUT;
    short8 qf[2];
    qf[0] = *reinterpret_cast<const short8*>(Qbase + lkhi * 8);
    qf[1] = *reinterpret_cast<const short8*>(Qbase + 32 + lkhi * 8);

    f32x4 o[4] = {};
    float m_run = -INFINITY, l_run = 0.f;   // stats for q = qloc (log2 domain)

    const unsigned short* Kg = kb + (size_t)b * S_ * DOUT;
    const unsigned short* Vg = vtb + (size_t)b * DOUT * S_;
    char* pw = reinterpret_cast<char*>(p_lds[wv]);

    int srow_lo = (lane >> 3);             // 0..7
    int schunk = (lane & 7) * 16;          // within-row byte
    int soff = schunk ^ (srow_lo << 4);    // inverse-swizzled source byte

    int kv_beg = c * 8;
    int kv_end = min(kv_beg + 8, qt + 1);
    int cur = 0;

#define STAGE(buf, kvt_) do {                                                  \
    int kv0_ = (kvt_) * KVB;                                                   \
    for (int h = 0; h < 2; ++h) {                                              \
        int r_ = wv * 16 + h * 8 + srow_lo;                                    \
        const char* gk_ = (const char*)(Kg + (size_t)(kv0_ + r_) * DOUT) + soff; \
        gload_lds16(gk_, (char*)k_lds[buf] + wv * 2048 + h * 1024);            \
        const char* gv_ = (const char*)(Vg + (size_t)r_ * S_ + kv0_) + soff;   \
        gload_lds16(gv_, (char*)v_lds[buf] + wv * 2048 + h * 1024);            \
    }                                                                          \
} while (0)

    STAGE(0, kv_beg);
    asm volatile("s_waitcnt vmcnt(0)" ::: "memory");
    __builtin_amdgcn_s_barrier();
    asm volatile("" ::: "memory");

    for (int kvt = kv_beg; kvt < kv_end; ++kvt) {
        if (kvt + 1 < kv_end) STAGE(cur ^ 1, kvt + 1);  // prefetch under compute

        const char* kl = (const char*)k_lds[cur];
        const char* vl = (const char*)v_lds[cur];

        // swapped QK^T: sc[ct][r] = S[q=qloc][kv = ct*16+lkhi4+r]
        f32x4 sc[4];
        __builtin_amdgcn_s_setprio(1);
        for (int ct = 0; ct < 4; ++ct) {
            f32x4 a = {};
            for (int ds = 0; ds < 2; ++ds) {
                int r = ct * 16 + lrow;
                int byte = (r * 128 + (ds * 32 + lkhi * 8) * 2) ^ ((r & 7) << 4);
                short8 kf = *reinterpret_cast<const short8*>(kl + byte);
                a = __builtin_amdgcn_mfma_f32_16x16x32_bf16(kf, qf[ds], a, 0, 0, 0);
            }
            sc[ct] = a;
        }
        __builtin_amdgcn_s_setprio(0);

        // causal mask (diag tile only): kv_local > q_local (incl. wave offset!)
        if (kvt == qt) {
            for (int ct = 0; ct < 4; ++ct)
                for (int r = 0; r < 4; ++r)
                    if (ct * 16 + lkhi4 + r > qloc) sc[ct][r] = -INFINITY;
        }

        // row max: in-lane tree + xor16/xor32
        float mx4[4];
        for (int ct = 0; ct < 4; ++ct)
            mx4[ct] = fmaxf(fmaxf(sc[ct][0], sc[ct][1]), fmaxf(sc[ct][2], sc[ct][3]));
        float mxl = fmaxf(fmaxf(mx4[0], mx4[1]), fmaxf(mx4[2], mx4[3]));
        mxl = fmaxf(mxl, __shfl_xor(mxl, 16));
        mxl = fmaxf(mxl, __shfl_xor(mxl, 32));
        float mnew = fmaxf(m_run, mxl);
        float corr = fast_exp2(m_run - mnew);

        // P = exp2(S - mnew); row sum
        float s4[4];
        for (int ct = 0; ct < 4; ++ct) {
            sc[ct][0] = fast_exp2(sc[ct][0] - mnew);
            sc[ct][1] = fast_exp2(sc[ct][1] - mnew);
            sc[ct][2] = fast_exp2(sc[ct][2] - mnew);
            sc[ct][3] = fast_exp2(sc[ct][3] - mnew);
            s4[ct] = (sc[ct][0] + sc[ct][1]) + (sc[ct][2] + sc[ct][3]);
        }
        float rs = (s4[0] + s4[1]) + (s4[2] + s4[3]);
        rs += __shfl_xor(rs, 16);
        rs += __shfl_xor(rs, 32);
        l_run = l_run * corr + rs;
        m_run = mnew;

        // rescale O (o[ct2][r] is row q=lkhi4+r; corr lives in lane lkhi4+r)
        float corrq[4];
        for (int r = 0; r < 4; ++r) corrq[r] = __shfl(corr, lkhi4 + r);
        for (int ct2 = 0; ct2 < 4; ++ct2)
            for (int r = 0; r < 4; ++r)
                o[ct2][r] *= corrq[r];

        // P -> per-wave LDS (A-layout source): row=q=lrow, col=kv, b64 packed
        for (int ct = 0; ct < 4; ++ct) {
            __hip_bfloat162 h0 = __float22bfloat162_rn({sc[ct][0], sc[ct][1]});
            __hip_bfloat162 h1 = __float22bfloat162_rn({sc[ct][2], sc[ct][3]});
            uint2 pk;
            pk.x = *reinterpret_cast<unsigned*>(&h0);
            pk.y = *reinterpret_cast<unsigned*>(&h1);
            int byte = (lrow * 128 + (ct * 16 + lkhi4) * 2) ^ ((lrow & 7) << 4);
            *reinterpret_cast<uint2*>(pw + byte) = pk;
        }

        // PV: A = P (rows=q), B = Vt (cols=d, k=kv contiguous)
        __builtin_amdgcn_s_setprio(1);
        for (int ct2 = 0; ct2 < 4; ++ct2) {
            for (int ks = 0; ks < 2; ++ks) {
                int pbyte = (lrow * 128 + (ks * 32 + lkhi * 8) * 2) ^ ((lrow & 7) << 4);
                short8 pf = *reinterpret_cast<const short8*>(pw + pbyte);
                int vr = ct2 * 16 + lrow;
                int vbyte = (vr * 128 + (ks * 32 + lkhi * 8) * 2) ^ ((vr & 7) << 4);
                short8 vf = *reinterpret_cast<const short8*>(vl + vbyte);
                o[ct2] = __builtin_amdgcn_mfma_f32_16x16x32_bf16(pf, vf, o[ct2], 0, 0, 0);
            }
        }
        __builtin_amdgcn_s_setprio(0);
        __syncthreads();   // drains the prefetch issued at loop top
        cur ^= 1;
    }
#undef STAGE

    // write partials (unnormalized O + per-row m,l in log2 domain)
    float* Op = Opart + ((size_t)b * NCHUNK_TOT + x) * (64 * 64);
    float* Ml = ml + ((size_t)b * NCHUNK_TOT + x) * (64 * 2);
    for (int r = 0; r < 4; ++r) {
        int qr = wv * 16 + lkhi4 + r;
        for (int ct2 = 0; ct2 < 4; ++ct2)
            Op[qr * 64 + ct2 * 16 + lrow] = o[ct2][r];
    }
    if (lkhi == 0) {
        int qr = wv * 16 + lrow;
        Ml[qr * 2 + 0] = m_run;
        Ml[qr * 2 + 1] = l_run;
    }
}

// ---------------------------------------------------------------------------
// Kernel 2b: combine partials (log2-domain m). grid (64 qtiles, B), 256 thr.
// ---------------------------------------------------------------------------
__global__ __launch_bounds__(256) void attn_combine(
    const float* __restrict__ Opart, const float* __restrict__ ml,
    float* __restrict__ out)
{
    int qt = blockIdx.x, b = blockIdx.y;
    int m = qt >> 3;
    int nch = m + 1;
    int cbase = 4 * m * (m + 1) + (qt - 8 * m) * nch;

    int r = threadIdx.x >> 2;
    int cg = (threadIdx.x & 3) * 16;

    float M = -INFINITY;
    for (int c = 0; c < nch; ++c)
        M = fmaxf(M, ml[(((size_t)b * NCHUNK_TOT + cbase + c) * 64 + r) * 2]);

    float L = 0.f;
    f32x4 acc[4] = {};
    for (int c = 0; c < nch; ++c) {
        size_t ci = (size_t)b * NCHUNK_TOT + cbase + c;
        float mc = ml[(ci * 64 + r) * 2 + 0];
        float lc = ml[(ci * 64 + r) * 2 + 1];
        float w = fast_exp2(mc - M);
        L += lc * w;
        const f32x4* Op = reinterpret_cast<const f32x4*>(Opart + ci * (64 * 64) + r * 64 + cg);
        for (int i = 0; i < 4; ++i) {
            f32x4 v = Op[i];
            acc[i] += v * w;
        }
    }
    float inv = 1.f / L;
    f32x4* dst = reinterpret_cast<f32x4*>(out + (((size_t)b * S_) + qt * 64 + r) * DOUT + cg);
    for (int i = 0; i < 4; ++i)
        dst[i] = acc[i] * inv;
}

extern "C" void kernel_launch(void* const* d_in, const int* in_sizes, int n_in,
                              void* d_out, int out_size, void* d_ws, size_t ws_size,
                              hipStream_t stream) {
    const float* key_in = (const float*)d_in[0];
    const float* val_in = (const float*)d_in[1];
    const float* qry_in = (const float*)d_in[2];
    const float* Wk = (const float*)d_in[3];
    const float* Wv = (const float*)d_in[4];
    const float* Wq = (const float*)d_in[5];
    float* out = (float*)d_out;

    char* ws = (char*)d_ws;
    size_t off = 0;
    unsigned short* qb  = (unsigned short*)(ws + off); off += (size_t)B_ * S_ * DOUT * 2;
    unsigned short* kb  = (unsigned short*)(ws + off); off += (size_t)B_ * S_ * DOUT * 2;
    unsigned short* vtb = (unsigned short*)(ws + off); off += (size_t)B_ * S_ * DOUT * 2;
    unsigned short* wt  = (unsigned short*)(ws + off); off += (size_t)3 * DIN * DOUT * 2;
    float* Opart = (float*)(ws + off); off += (size_t)B_ * NCHUNK_TOT * 64 * 64 * 4;
    float* ml    = (float*)(ws + off); off += (size_t)B_ * NCHUNK_TOT * 64 * 2 * 4;

    wt_kernel<<<dim3(8, 3), 256, 0, stream>>>(Wq, Wk, Wv, wt);
    proj_kernel<<<dim3(256, 3), 256, 0, stream>>>(qry_in, key_in, val_in, wt, qb, kb, vtb);
    attn_part<<<dim3(NCHUNK_TOT, B_), 256, 0, stream>>>(qb, kb, vtb, Opart, ml);
    attn_combine<<<dim3(S_ / QB, B_), 256, 0, stream>>>(Opart, ml, out);
}